// Round 10
// baseline (564.184 us; speedup 1.0000x reference)
//
#include <hip/hip_runtime.h>
#include <math.h>

#define N_ATOMS 50000
#define D 32
#define E_EDGES 300000
#define BD 16
#define SW 544                                // 17*32 (16 bond ch + 1 bias ch)
#define SCAN_BLOCKS ((N_ATOMS + 255) / 256)   // 196
#define GRU_TILE 8
#define GRU_NT (N_ATOMS / GRU_TILE)           // 6250

#define NB 32                                 // src nodes per block (4 per half-wave)
#define FBLOCKS ((N_ATOMS + NB - 1) / NB)     // 1563

__device__ __forceinline__ float sigmoidf_(float x) {
    return 1.0f / (1.0f + __expf(-x));
}

// ---------- precompute (once per launch) ----------

// WTj[j*544 + b*32 + i] = W[b,i,j]  (b<16: kernel.reshape(16,32,32); b=16: Bm)
__global__ void k_build_wt(const float* __restrict__ kern,
                           const float* __restrict__ bias,
                           float* __restrict__ WTj) {
    int idx = blockIdx.x * 256 + threadIdx.x;
    if (idx >= 32 * SW) return;
    int j = idx / SW;
    int r = idx - j * SW;
    int b = r >> 5, i = r & 31;
    WTj[idx] = (b < BD) ? kern[b * 1024 + i * 32 + j] : bias[i * 32 + j];
}

// histogram over a strided column of pair (col=1: src, col=0: dst)
__global__ void k_hist(const int* __restrict__ pair, int* __restrict__ deg, int col) {
    int e = blockIdx.x * 256 + threadIdx.x;
    if (e < E_EDGES) atomicAdd(&deg[pair[2 * e + col]], 1);
}

__global__ void k_scan1(const int* __restrict__ deg, int* __restrict__ offs,
                        int* __restrict__ bsums) {
    __shared__ int sm[256];
    int t = threadIdx.x, gid = blockIdx.x * 256 + t;
    int v = (gid < N_ATOMS) ? deg[gid] : 0;
    sm[t] = v;
    __syncthreads();
    for (int off = 1; off < 256; off <<= 1) {
        int x = (t >= off) ? sm[t - off] : 0;
        __syncthreads();
        sm[t] += x;
        __syncthreads();
    }
    if (gid < N_ATOMS) offs[gid] = sm[t] - v;
    if (t == 255) bsums[blockIdx.x] = sm[255];
}

__global__ void k_scan2(const int* __restrict__ bsums, int* __restrict__ boffs, int nb) {
    __shared__ int sm[256];
    int t = threadIdx.x;
    int v = (t < nb) ? bsums[t] : 0;
    sm[t] = v;
    __syncthreads();
    for (int off = 1; off < 256; off <<= 1) {
        int x = (t >= off) ? sm[t - off] : 0;
        __syncthreads();
        sm[t] += x;
        __syncthreads();
    }
    if (t < nb) boffs[t] = sm[t] - v;
}

__global__ void k_scan3(int* __restrict__ offs, const int* __restrict__ boffs) {
    int gid = blockIdx.x * 256 + threadIdx.x;
    if (gid < N_ATOMS) offs[gid] += boffs[blockIdx.x];
}

// Permute edges to src-CSR order; materialize bond rows and dst in that order.
__global__ void k_scatter_perm(const int* __restrict__ pair, const int* __restrict__ offs,
                               int* __restrict__ cursor, const float* __restrict__ bond,
                               float* __restrict__ bond_perm, int* __restrict__ dstid) {
    int e = blockIdx.x * 256 + threadIdx.x;
    if (e >= E_EDGES) return;
    int d = pair[2 * e], s = pair[2 * e + 1];
    int pos = offs[s] + atomicAdd(&cursor[s], 1);
    dstid[pos] = d;
    const float4* src4 = (const float4*)(bond + (size_t)e * BD);
    float4* dst4 = (float4*)(bond_perm + (size_t)pos * BD);
    dst4[0] = src4[0];
    dst4[1] = src4[1];
    dst4[2] = src4[2];
    dst4[3] = src4[3];
}

// wpos[p] = slot of src-CSR edge p in dst-CSR order
__global__ void k_dstpos(const int* __restrict__ dstid, const int* __restrict__ offs2,
                         int* __restrict__ cursor2, int* __restrict__ wpos) {
    int p = blockIdx.x * 256 + threadIdx.x;
    if (p >= E_EDGES) return;
    int d = dstid[p];
    wpos[p] = offs2[d] + atomicAdd(&cursor2[d], 1);
}

#define EDGE_FMA(M, B0, B1, B2, B3, YN) do {            \
    M = fmaf(B0.x, YN[0],  M); M = fmaf(B0.y, YN[1],  M); \
    M = fmaf(B0.z, YN[2],  M); M = fmaf(B0.w, YN[3],  M); \
    M = fmaf(B1.x, YN[4],  M); M = fmaf(B1.y, YN[5],  M); \
    M = fmaf(B1.z, YN[6],  M); M = fmaf(B1.w, YN[7],  M); \
    M = fmaf(B2.x, YN[8],  M); M = fmaf(B2.y, YN[9],  M); \
    M = fmaf(B2.z, YN[10], M); M = fmaf(B2.w, YN[11], M); \
    M = fmaf(B3.x, YN[12], M); M = fmaf(B3.y, YN[13], M); \
    M = fmaf(B3.z, YN[14], M); M = fmaf(B3.w, YN[15], M); \
} while (0)

// ---------- message kernel: projection in regs + plain scatter-stores ----------
// Per half-wave: 4 src nodes. Phase A: y[n][b] in registers (lane = feature i).
// Phase B: walk outgoing edges (linear bond_perm/wpos streams), compute msg,
// STORE (not atomic) to msg_d[wpos[p]] -- dst-CSR slot. No RMW, no coherence
// round-trip; randomness rides the fire-and-forget write path.
__global__ __launch_bounds__(256, 2)
void k_msg(const float* __restrict__ h_in, float* __restrict__ msg_d,
           const float* __restrict__ bond_perm, const int* __restrict__ wpos,
           const float* __restrict__ WTj,
           const int* __restrict__ offs, const int* __restrict__ deg) {
    __shared__ float h_lds[NB][33];       // 4224 B

    const int t = threadIdx.x;
    const int bbase = blockIdx.x * NB;
    const int i = t & 31;                 // feature lane
    const int grp = t >> 5;               // half-wave 0..7
    const int hn0 = grp * 4;

#pragma unroll
    for (int k = 0; k < 4; ++k) {
        const int idx = t + 256 * k;
        const int n = idx >> 5, j = idx & 31;
        const int node = bbase + n;
        h_lds[n][j] = (node < N_ATOMS) ? h_in[(size_t)node * D + j] : 0.f;
    }

    int stv[4], env[4];
#pragma unroll
    for (int n = 0; n < 4; ++n) {
        const int node = bbase + hn0 + n;
        const bool ok = (node < N_ATOMS);
        const int o = ok ? offs[node] : 0;
        stv[n] = o;
        env[n] = o + (ok ? deg[node] : 0);
    }
    __syncthreads();

    // Phase A: y[n][b] = sum_j WTj[j][b*32+i] * h[node_n][j]
    float y[4][17];
#pragma unroll
    for (int n = 0; n < 4; ++n)
#pragma unroll
        for (int b = 0; b < 17; ++b) y[n][b] = 0.f;

    for (int j = 0; j < 32; ++j) {
        float wv[17];
#pragma unroll
        for (int b = 0; b < 17; ++b)
            wv[b] = WTj[j * SW + b * 32 + i];
#pragma unroll
        for (int n = 0; n < 4; ++n) {
            const float hv = h_lds[hn0 + n][j];
#pragma unroll
            for (int b = 0; b < 17; ++b)
                y[n][b] = fmaf(wv[b], hv, y[n][b]);
        }
    }

    // Phase B: linear streams in, 128B scatter-stores out
#pragma unroll
    for (int n = 0; n < 4; ++n) {
        int p = stv[n];
        const int e = env[n];
        for (; p + 2 <= e; p += 2) {
            const float4* bp0 = (const float4*)(bond_perm + (size_t)p * BD);
            const float4* bp1 = (const float4*)(bond_perm + (size_t)(p + 1) * BD);
            const int w0 = wpos[p];
            const int w1 = wpos[p + 1];
            const float4 a0 = bp0[0], a1 = bp0[1], a2 = bp0[2], a3 = bp0[3];
            const float4 c0 = bp1[0], c1 = bp1[1], c2 = bp1[2], c3 = bp1[3];
            float m0 = y[n][16];
            float m1 = y[n][16];
            EDGE_FMA(m0, a0, a1, a2, a3, y[n]);
            EDGE_FMA(m1, c0, c1, c2, c3, y[n]);
            msg_d[(size_t)w0 * D + i] = m0;
            msg_d[(size_t)w1 * D + i] = m1;
        }
        if (p < e) {
            const float4* bp0 = (const float4*)(bond_perm + (size_t)p * BD);
            const int w0 = wpos[p];
            const float4 a0 = bp0[0], a1 = bp0[1], a2 = bp0[2], a3 = bp0[3];
            float m0 = y[n][16];
            EDGE_FMA(m0, a0, a1, a2, a3, y[n]);
            msg_d[(size_t)w0 * D + i] = m0;
        }
    }
}

// ---------- aggregate + GRU fused ----------
// Per half-wave: one dst node per tile iteration. msg_d is dst-CSR ordered ->
// each node's messages are CONTIGUOUS 128B rows (linear stream). Sum in regs,
// stage into x_lds, then GRU exactly as before.
__global__ __launch_bounds__(256, 2)
void k_aggru(const float* __restrict__ msg_d,
             const int* __restrict__ offs2, const int* __restrict__ deg2,
             const float* __restrict__ h_in, float* __restrict__ h_out,
             const float* __restrict__ Wih, const float* __restrict__ Whh,
             const float* __restrict__ bih, const float* __restrict__ bhh) {
    __shared__ float Wih_s[96][33];
    __shared__ float Whh_s[96][33];
    __shared__ float bih_s[96], bhh_s[96];
    __shared__ float x_lds[GRU_TILE][32];
    __shared__ float h_lds[GRU_TILE][32];

    const int t = threadIdx.x;

    for (int idx = t; idx < 96 * 32; idx += 256) {
        const int o = idx >> 5, jj = idx & 31;
        Wih_s[o][jj] = Wih[idx];
        Whh_s[o][jj] = Whh[idx];
    }
    if (t < 96) { bih_s[t] = bih[t]; bhh_s[t] = bhh[t]; }

    const int r = t >> 5;   // node within octet / half-wave id
    const int i = t & 31;   // feature lane
    const int stride = gridDim.x;

    for (int tile = blockIdx.x; tile < GRU_NT; tile += stride) {
        const int node = tile * GRU_TILE + r;
        // ---- gather-sum my node's contiguous msg rows
        const int st = offs2[node];
        const int en = st + deg2[node];
        float acc = 0.f;
        int p = st;
        for (; p + 4 <= en; p += 4) {     // 4 independent loads in flight
            const float a0 = msg_d[(size_t)(p + 0) * D + i];
            const float a1 = msg_d[(size_t)(p + 1) * D + i];
            const float a2 = msg_d[(size_t)(p + 2) * D + i];
            const float a3 = msg_d[(size_t)(p + 3) * D + i];
            acc += (a0 + a1) + (a2 + a3);
        }
        for (; p < en; ++p) acc += msg_d[(size_t)p * D + i];
        x_lds[r][i] = acc;
        ((float*)h_lds)[t] = h_in[tile * 256 + t];
        __syncthreads();

        float gri = bih_s[i],      grh = bhh_s[i];
        float gzi = bih_s[32 + i], gzh = bhh_s[32 + i];
        float gni = bih_s[64 + i], gnh = bhh_s[64 + i];
#pragma unroll 8
        for (int jj = 0; jj < 32; ++jj) {
            const float xv = x_lds[r][jj];
            const float hv = h_lds[r][jj];
            gri = fmaf(Wih_s[i][jj],      xv, gri);
            gzi = fmaf(Wih_s[32 + i][jj], xv, gzi);
            gni = fmaf(Wih_s[64 + i][jj], xv, gni);
            grh = fmaf(Whh_s[i][jj],      hv, grh);
            gzh = fmaf(Whh_s[32 + i][jj], hv, gzh);
            gnh = fmaf(Whh_s[64 + i][jj], hv, gnh);
        }
        const float rg = sigmoidf_(gri + grh);
        const float zg = sigmoidf_(gzi + gzh);
        float xn = gni + rg * gnh;
        xn = fminf(fmaxf(xn, -15.f), 15.f);
        const float e2 = __expf(2.f * xn);
        const float ng = (e2 - 1.f) / (e2 + 1.f);
        h_out[tile * 256 + t] = (1.f - zg) * ng + zg * h_lds[r][i];
        __syncthreads();
    }
}

// ---------- launch ----------
extern "C" void kernel_launch(void* const* d_in, const int* in_sizes, int n_in,
                              void* d_out, int out_size, void* d_ws, size_t ws_size,
                              hipStream_t stream) {
    const float* atom = (const float*)d_in[0];
    const float* bond = (const float*)d_in[1];
    const int*   pair = (const int*)d_in[2];
    const float* kern = (const float*)d_in[3];
    const float* bias = (const float*)d_in[4];
    const float* Wih  = (const float*)d_in[5];
    const float* Whh  = (const float*)d_in[6];
    const float* bih  = (const float*)d_in[7];
    const float* bhh  = (const float*)d_in[8];
    float* out = (float*)d_out;

    char* w = (char*)d_ws;
    auto alloc = [&](size_t bytes) {
        char* p = w;
        w += (bytes + 255) & ~size_t(255);
        return p;
    };
    float* hA        = (float*)alloc((size_t)N_ATOMS * D * 4);
    float* WTj       = (float*)alloc((size_t)32 * SW * 4);
    int*   deg       = (int*)alloc((size_t)N_ATOMS * 4);
    int*   offs      = (int*)alloc((size_t)N_ATOMS * 4);
    int*   deg2      = (int*)alloc((size_t)N_ATOMS * 4);
    int*   offs2     = (int*)alloc((size_t)N_ATOMS * 4);
    int*   cursor    = (int*)alloc((size_t)N_ATOMS * 4);
    int*   cursor2   = (int*)alloc((size_t)N_ATOMS * 4);
    int*   bsums     = (int*)alloc(256 * 4);
    int*   boffs     = (int*)alloc(256 * 4);
    int*   dstid     = (int*)alloc((size_t)E_EDGES * 4);
    int*   wpos      = (int*)alloc((size_t)E_EDGES * 4);
    float* bond_perm = (float*)alloc((size_t)E_EDGES * BD * 4);
    float* msg_d     = (float*)alloc((size_t)E_EDGES * D * 4);   // 38.4 MB

    hipMemsetAsync(deg, 0, (size_t)N_ATOMS * 4, stream);
    hipMemsetAsync(deg2, 0, (size_t)N_ATOMS * 4, stream);
    hipMemsetAsync(cursor, 0, (size_t)N_ATOMS * 4, stream);
    hipMemsetAsync(cursor2, 0, (size_t)N_ATOMS * 4, stream);

    k_build_wt<<<(32 * SW + 255) / 256, 256, 0, stream>>>(kern, bias, WTj);
    // src-CSR
    k_hist<<<(E_EDGES + 255) / 256, 256, 0, stream>>>(pair, deg, 1);
    k_scan1<<<SCAN_BLOCKS, 256, 0, stream>>>(deg, offs, bsums);
    k_scan2<<<1, 256, 0, stream>>>(bsums, boffs, SCAN_BLOCKS);
    k_scan3<<<SCAN_BLOCKS, 256, 0, stream>>>(offs, boffs);
    // dst-CSR
    k_hist<<<(E_EDGES + 255) / 256, 256, 0, stream>>>(pair, deg2, 0);
    k_scan1<<<SCAN_BLOCKS, 256, 0, stream>>>(deg2, offs2, bsums);
    k_scan2<<<1, 256, 0, stream>>>(bsums, boffs, SCAN_BLOCKS);
    k_scan3<<<SCAN_BLOCKS, 256, 0, stream>>>(offs2, boffs);
    // permutations
    k_scatter_perm<<<(E_EDGES + 255) / 256, 256, 0, stream>>>(pair, offs, cursor,
                                                              bond, bond_perm, dstid);
    k_dstpos<<<(E_EDGES + 255) / 256, 256, 0, stream>>>(dstid, offs2, cursor2, wpos);

    const float* hsrc = atom;
    float* hdst[4] = { hA, out, hA, out };
    for (int s = 0; s < 4; ++s) {
        k_msg<<<FBLOCKS, 256, 0, stream>>>(hsrc, msg_d, bond_perm, wpos,
                                           WTj, offs, deg);
        k_aggru<<<2048, 256, 0, stream>>>(msg_d, offs2, deg2, hsrc, hdst[s],
                                          Wih, Whh, bih, bhh);
        hsrc = hdst[s];
    }
}